// Round 5
// baseline (300.082 us; speedup 1.0000x reference)
//
#include <hip/hip_runtime.h>
#include <hip/hip_bf16.h>
#include <math.h>

#define NF_IN 512
#define NF_OUT 256
#define HEADS 6
#define NCOLS (HEADS * NF_OUT)   // 1536
#define SLOPE 0.2f

typedef __attribute__((ext_vector_type(8))) short short8;
typedef __attribute__((ext_vector_type(4))) float f32x4;

__device__ __forceinline__ float bf2f(unsigned short u) {
  unsigned int x = ((unsigned int)u) << 16;
  return __uint_as_float(x);
}
__device__ __forceinline__ unsigned short f2bf(float f) {
  unsigned int x = __float_as_uint(f);
  unsigned int lsb = (x >> 16) & 1u;
  x += 0x7fffu + lsb;
  return (unsigned short)(x >> 16);
}

__device__ __forceinline__ void gload_lds16(const void* g, void* l) {
  __builtin_amdgcn_global_load_lds(
      (const __attribute__((address_space(1))) void*)g,
      (__attribute__((address_space(3))) void*)l, 16, 0, 0);
}

// ---------------- zero init ----------------
__global__ void zero_kernel(int* __restrict__ p, int n) {
  int i = blockIdx.x * blockDim.x + threadIdx.x;
  if (i < n) p[i] = 0;
}

// ---------------- fused: data->bf16 convert + coord matvec + coord scores ----------------
__global__ __launch_bounds__(256) void prep_data_kernel(
    const float* __restrict__ data, const float* __restrict__ W,
    const float* __restrict__ att_src, const float* __restrict__ att_dst,
    unsigned short* __restrict__ data_bf, float* __restrict__ xp,
    float* __restrict__ a_src, float* __restrict__ a_dst, int n_nodes, int m_pad) {
  __shared__ float Ws[NF_IN * 12];
  int t = threadIdx.x;
#pragma unroll
  for (int i = 0; i < 6; ++i)
    *(float4*)(Ws + (i * 256 + t) * 4) = *(const float4*)(W + (i * 256 + t) * 4);
  __syncthreads();
  int warp = t >> 6, lane = t & 63;
  int n = blockIdx.x * 4 + warp;
  if (n >= m_pad) return;
  if (n >= n_nodes) {  // pad rows: zero bf16
    ushort4 z = {0, 0, 0, 0};
    *(ushort4*)(data_bf + (size_t)n * NF_IN + lane * 4) = z;
    *(ushort4*)(data_bf + (size_t)n * NF_IN + 256 + lane * 4) = z;
    return;
  }
  const float* row = data + (size_t)n * NF_IN;
  float x[8];
  *(float4*)(x) = *(const float4*)(row + lane * 4);
  *(float4*)(x + 4) = *(const float4*)(row + 256 + lane * 4);
  ushort4 u0, u1;
  u0.x = f2bf(x[0]); u0.y = f2bf(x[1]); u0.z = f2bf(x[2]); u0.w = f2bf(x[3]);
  u1.x = f2bf(x[4]); u1.y = f2bf(x[5]); u1.z = f2bf(x[6]); u1.w = f2bf(x[7]);
  *(ushort4*)(data_bf + (size_t)n * NF_IN + lane * 4) = u0;
  *(ushort4*)(data_bf + (size_t)n * NF_IN + 256 + lane * 4) = u1;
  float acc[12];
#pragma unroll
  for (int o = 0; o < 12; ++o) acc[o] = 0.f;
#pragma unroll
  for (int j = 0; j < 8; ++j) {
    int c = (j < 4) ? (lane * 4 + j) : (256 + lane * 4 + (j - 4));
    const float* wr = Ws + c * 12;
#pragma unroll
    for (int o = 0; o < 12; ++o) acc[o] += x[j] * wr[o];
  }
#pragma unroll
  for (int o = 0; o < 12; ++o) {
#pragma unroll
    for (int off = 32; off; off >>= 1) acc[o] += __shfl_xor(acc[o], off, 64);
  }
  if (lane == 0) {
    float* xr = xp + (size_t)n * 12;
#pragma unroll
    for (int o = 0; o < 12; ++o) xr[o] = acc[o];
#pragma unroll
    for (int h = 0; h < HEADS; ++h) {
      a_src[n * HEADS + h] = acc[2 * h] * att_src[2 * h] + acc[2 * h + 1] * att_src[2 * h + 1];
      a_dst[n * HEADS + h] = acc[2 * h] * att_dst[2 * h] + acc[2 * h + 1] * att_dst[2 * h + 1];
    }
  }
}

// ---------------- W_feat [512][1536] fp32 -> Wt [1536][512] bf16 ----------------
__global__ __launch_bounds__(256) void transpose_w_kernel(
    const float* __restrict__ W, unsigned short* __restrict__ Wt) {
  __shared__ float tileS[32][33];
  int c0 = blockIdx.x * 32;
  int k0 = blockIdx.y * 32;
  int t = threadIdx.x;
  int tr = t >> 5;
  int tc = t & 31;
#pragma unroll
  for (int j = 0; j < 4; ++j)
    tileS[tr * 4 + j][tc] = W[(size_t)(k0 + tr * 4 + j) * NCOLS + c0 + tc];
  __syncthreads();
#pragma unroll
  for (int j = 0; j < 4; ++j)
    Wt[(size_t)(c0 + tr * 4 + j) * NF_IN + k0 + tc] = f2bf(tileS[tc][tr * 4 + j]);
}

// ---------------- bf16 MFMA GEMM + fused attention-score epilogue ----------------
#define GBM 128
#define GBN 128
#define GBK 32
__global__ __launch_bounds__(256) void gemm_mfma_kernel(
    const unsigned short* __restrict__ A, const unsigned short* __restrict__ Bt,
    unsigned short* __restrict__ C, const float* __restrict__ att_src,
    const float* __restrict__ att_dst, float* __restrict__ a_srcF,
    float* __restrict__ a_dstF, int M) {
  __shared__ __align__(16) unsigned short sA[GBM * GBK];
  __shared__ __align__(16) unsigned short sB[GBN * GBK];
  const int tid = threadIdx.x;
  const int wid = tid >> 6;
  const int lane = tid & 63;
  const int row0 = blockIdx.y * GBM;
  const int col0 = blockIdx.x * GBN;
  const int wr = (wid >> 1) * 64;
  const int wc = (wid & 1) * 64;

  f32x4 acc[4][4] = {};

  const int arow = tid >> 2;
  const int kseg = tid & 3;
  const unsigned short* gA = A + (size_t)(row0 + arow) * NF_IN + kseg * 8;
  const unsigned short* gB = Bt + (size_t)(col0 + arow) * NF_IN + kseg * 8;
  unsigned short* lA = sA + wid * 512;
  unsigned short* lB = sB + wid * 512;

  const int fr = lane & 15;
  const int fk = (lane >> 4) * 8;

  for (int k0 = 0; k0 < NF_IN; k0 += GBK) {
    gload_lds16(gA + k0, lA);
    gload_lds16(gA + 64 * NF_IN + k0, lA + 2048);
    gload_lds16(gB + k0, lB);
    gload_lds16(gB + 64 * NF_IN + k0, lB + 2048);
    __syncthreads();
    short8 af[4], bfr[4];
#pragma unroll
    for (int m = 0; m < 4; ++m)
      af[m] = *(const short8*)(sA + (wr + m * 16 + fr) * GBK + fk);
#pragma unroll
    for (int nn = 0; nn < 4; ++nn)
      bfr[nn] = *(const short8*)(sB + (wc + nn * 16 + fr) * GBK + fk);
#pragma unroll
    for (int m = 0; m < 4; ++m)
#pragma unroll
      for (int nn = 0; nn < 4; ++nn)
        acc[m][nn] = __builtin_amdgcn_mfma_f32_16x16x32_bf16(af[m], bfr[nn],
                                                             acc[m][nn], 0, 0, 0);
    __syncthreads();
  }

  const int dcol = lane & 15;
  const int g4 = (lane >> 4) * 4;
#pragma unroll
  for (int m = 0; m < 4; ++m) {
#pragma unroll
    for (int i = 0; i < 4; ++i) {
      int r = row0 + wr + m * 16 + g4 + i;
      if (r < M) {
#pragma unroll
        for (int nn = 0; nn < 4; ++nn)
          C[(size_t)r * NCOLS + col0 + wc + nn * 16 + dcol] = f2bf(acc[m][nn][i]);
      }
    }
  }

  // fused attention scores: all cols of this block lie in one head
  {
    const int head = blockIdx.x >> 1;           // NCOLS/GBN = 12 blocks, 2 per head
    const int cb = (col0 & 255) + wc + dcol;    // col-in-head for nn=0
    float avs[4], avd[4];
#pragma unroll
    for (int nn = 0; nn < 4; ++nn) {
      avs[nn] = att_src[head * NF_OUT + cb + nn * 16];
      avd[nn] = att_dst[head * NF_OUT + cb + nn * 16];
    }
#pragma unroll
    for (int m = 0; m < 4; ++m) {
#pragma unroll
      for (int i = 0; i < 4; ++i) {
        float ps = acc[m][0][i] * avs[0] + acc[m][1][i] * avs[1] +
                   acc[m][2][i] * avs[2] + acc[m][3][i] * avs[3];
        float pd = acc[m][0][i] * avd[0] + acc[m][1][i] * avd[1] +
                   acc[m][2][i] * avd[2] + acc[m][3][i] * avd[3];
#pragma unroll
        for (int off = 1; off < 16; off <<= 1) {
          ps += __shfl_xor(ps, off, 64);
          pd += __shfl_xor(pd, off, 64);
        }
        int r = row0 + wr + m * 16 + g4 + i;
        if (dcol == 0 && r < M) {
          atomicAdd(&a_srcF[r * HEADS + head], ps);
          atomicAdd(&a_dstF[r * HEADS + head], pd);
        }
      }
    }
  }
}

// ---------------- edge counting ----------------
__global__ void count_edges_kernel(const int* __restrict__ ei, int E, int Et,
                                   int* __restrict__ counts) {
  int e = blockIdx.x * blockDim.x + threadIdx.x;
  if (e >= Et) return;
  int d = (e < E) ? ei[E + e] : (e - E);
  atomicAdd(&counts[d], 1);
}

// ---------------- fast single-block exclusive scan -> indptr ----------------
__global__ __launch_bounds__(1024) void scan_kernel(const int* __restrict__ counts,
                                                    int* __restrict__ indptr, int n) {
  __shared__ int wsum[16];
  const int CH = (n + 1023) >> 10;
  int t = threadIdx.x, lane = t & 63, w = t >> 6;
  int base = t * CH;
  int run = 0;
  for (int i = 0; i < CH; ++i) {
    int idx = base + i;
    run += (idx < n) ? counts[idx] : 0;
  }
  int tot = run;
#pragma unroll
  for (int off = 1; off < 64; off <<= 1) {
    int x = __shfl_up(tot, off, 64);
    if (lane >= off) tot += x;
  }
  if (lane == 63) wsum[w] = tot;
  __syncthreads();
  if (t == 0) {
    int s = 0;
#pragma unroll
    for (int i = 0; i < 16; ++i) { int x = wsum[i]; wsum[i] = s; s += x; }
  }
  __syncthreads();
  int run2 = wsum[w] + (tot - run);
  if (t == 0) indptr[0] = 0;
  for (int i = 0; i < CH; ++i) {
    int idx = base + i;
    if (idx < n) {
      run2 += counts[idx];
      indptr[idx + 1] = run2;
    }
  }
}

// ---------------- scatter to CSR ----------------
__global__ void scatter_kernel(const int* __restrict__ ei, int E, int Et,
                               const int* __restrict__ indptr, int* __restrict__ fill,
                               int* __restrict__ csr_src) {
  int e = blockIdx.x * blockDim.x + threadIdx.x;
  if (e >= Et) return;
  int s, d;
  if (e < E) { s = ei[e]; d = ei[E + e]; } else { s = d = e - E; }
  int pos = indptr[d] + atomicAdd(&fill[d], 1);
  csr_src[pos] = s;
}

// ---------------- fused per (node, head) edge softmax: feat + coord in one walk ----------------
__global__ void softmax2_kernel(const float* __restrict__ asf, const float* __restrict__ adf,
                                const float* __restrict__ asc, const float* __restrict__ adc,
                                const int* __restrict__ indptr,
                                const int* __restrict__ csr_src,
                                float* __restrict__ coef_f, float* __restrict__ coef_c,
                                int n_nodes) {
  int gid = blockIdx.x * blockDim.x + threadIdx.x;
  if (gid >= n_nodes * HEADS) return;
  int n = gid / HEADS, h = gid - n * HEADS;
  int e0 = indptr[n], e1 = indptr[n + 1];
  float adF = adf[n * HEADS + h];
  float adC = adc[n * HEADS + h];
  float mxF = -1e30f, mxC = -1e30f;
  for (int p = e0; p < e1; ++p) {
    int s = csr_src[p];
    float vF = asf[s * HEADS + h] + adF;
    float vC = asc[s * HEADS + h] + adC;
    vF = (vF >= 0.f) ? vF : SLOPE * vF;
    vC = (vC >= 0.f) ? vC : SLOPE * vC;
    coef_f[(size_t)p * HEADS + h] = vF;
    coef_c[(size_t)p * HEADS + h] = vC;
    mxF = fmaxf(mxF, vF);
    mxC = fmaxf(mxC, vC);
  }
  float sF = 0.f, sC = 0.f;
  for (int p = e0; p < e1; ++p) {
    float eF = __expf(coef_f[(size_t)p * HEADS + h] - mxF);
    float eC = __expf(coef_c[(size_t)p * HEADS + h] - mxC);
    coef_f[(size_t)p * HEADS + h] = eF;
    coef_c[(size_t)p * HEADS + h] = eC;
    sF += eF;
    sC += eC;
  }
  float iF = 1.f / (sF + 1e-16f);
  float iC = 1.f / (sC + 1e-16f);
  for (int p = e0; p < e1; ++p) {
    coef_f[(size_t)p * HEADS + h] *= iF;
    coef_c[(size_t)p * HEADS + h] *= iC;
  }
}

// ---------------- feat aggregation: persistent wave-per-node, grid-stride ----------------
// Lane l, chunk j covers elems j*512 + l*8: head = 2j + (l>>5), col = (l&31)*8.
// Lane l and l^32 hold complementary head triples for the same cols -> one
// shfl_xor(32) finishes the head sum; lanes <32 store cols l*8..l*8+8.
__global__ __launch_bounds__(256) void agg_feat_kernel(
    const unsigned short* __restrict__ xp, const float* __restrict__ coef,
    const int* __restrict__ indptr, const int* __restrict__ csr_src,
    const float* __restrict__ bias, float* __restrict__ out, int n_nodes) {
  int lane = threadIdx.x & 63;
  int gw = blockIdx.x * 4 + (threadIdx.x >> 6);
  int nw = gridDim.x * 4;
  int hhalf = lane >> 5;
  const unsigned short* xpl = xp + lane * 8;

  for (int n = gw; n < n_nodes; n += nw) {
    int e0 = indptr[n], e1 = indptr[n + 1];
    float acc[3][8];
#pragma unroll
    for (int j = 0; j < 3; ++j)
#pragma unroll
      for (int i = 0; i < 8; ++i) acc[j][i] = 0.f;

    int p = e0;
    for (; p + 4 <= e1; p += 4) {
      int s0 = csr_src[p], s1 = csr_src[p + 1], s2 = csr_src[p + 2], s3 = csr_src[p + 3];
      const unsigned short* r0 = xpl + (size_t)s0 * NCOLS;
      const unsigned short* r1 = xpl + (size_t)s1 * NCOLS;
      const unsigned short* r2 = xpl + (size_t)s2 * NCOLS;
      const unsigned short* r3 = xpl + (size_t)s3 * NCOLS;
      ushort4 u[4][3], v[4][3];
#pragma unroll
      for (int j = 0; j < 3; ++j) {
        u[0][j] = *(const ushort4*)(r0 + j * 512);
        u[1][j] = *(const ushort4*)(r1 + j * 512);
        u[2][j] = *(const ushort4*)(r2 + j * 512);
        u[3][j] = *(const ushort4*)(r3 + j * 512);
        v[0][j] = *(const ushort4*)(r0 + j * 512 + 4);
        v[1][j] = *(const ushort4*)(r1 + j * 512 + 4);
        v[2][j] = *(const ushort4*)(r2 + j * 512 + 4);
        v[3][j] = *(const ushort4*)(r3 + j * 512 + 4);
      }
      float cf[4][3];
#pragma unroll
      for (int e = 0; e < 4; ++e)
#pragma unroll
        for (int j = 0; j < 3; ++j)
          cf[e][j] = coef[(size_t)(p + e) * HEADS + 2 * j + hhalf];
#pragma unroll
      for (int e = 0; e < 4; ++e)
#pragma unroll
        for (int j = 0; j < 3; ++j) {
          float c = cf[e][j];
          acc[j][0] += c * bf2f(u[e][j].x);
          acc[j][1] += c * bf2f(u[e][j].y);
          acc[j][2] += c * bf2f(u[e][j].z);
          acc[j][3] += c * bf2f(u[e][j].w);
          acc[j][4] += c * bf2f(v[e][j].x);
          acc[j][5] += c * bf2f(v[e][j].y);
          acc[j][6] += c * bf2f(v[e][j].z);
          acc[j][7] += c * bf2f(v[e][j].w);
        }
    }
    for (; p < e1; ++p) {
      int s0 = csr_src[p];
      const unsigned short* r0 = xpl + (size_t)s0 * NCOLS;
#pragma unroll
      for (int j = 0; j < 3; ++j) {
        float c = coef[(size_t)p * HEADS + 2 * j + hhalf];
        ushort4 a = *(const ushort4*)(r0 + j * 512);
        ushort4 b = *(const ushort4*)(r0 + j * 512 + 4);
        acc[j][0] += c * bf2f(a.x); acc[j][1] += c * bf2f(a.y);
        acc[j][2] += c * bf2f(a.z); acc[j][3] += c * bf2f(a.w);
        acc[j][4] += c * bf2f(b.x); acc[j][5] += c * bf2f(b.y);
        acc[j][6] += c * bf2f(b.z); acc[j][7] += c * bf2f(b.w);
      }
    }
    float r[8];
#pragma unroll
    for (int i = 0; i < 8; ++i) {
      r[i] = acc[0][i] + acc[1][i] + acc[2][i];
      r[i] += __shfl_xor(r[i], 32, 64);
    }
    if (lane < 32) {
      const float selu_scale = 1.0507009873554805f;
      const float selu_alpha = 1.6732632423543772f;
      int c0 = lane * 8;
#pragma unroll
      for (int i = 0; i < 8; ++i) {
        float v = r[i] * (1.f / HEADS) + bias[c0 + i];
        r[i] = (v > 0.f) ? selu_scale * v : selu_scale * selu_alpha * expm1f(v);
      }
      float4 o0, o1;
      o0.x = r[0]; o0.y = r[1]; o0.z = r[2]; o0.w = r[3];
      o1.x = r[4]; o1.y = r[5]; o1.z = r[6]; o1.w = r[7];
      *(float4*)(out + (size_t)n * NF_OUT + c0) = o0;
      *(float4*)(out + (size_t)n * NF_OUT + c0 + 4) = o1;
    }
  }
}

// ---------------- coord aggregation + boundary fix (2-edge ILP) ----------------
__global__ void agg_coord_kernel(const float* __restrict__ xpc,
                                 const float* __restrict__ coef,
                                 const int* __restrict__ indptr,
                                 const int* __restrict__ csr_src,
                                 const float* __restrict__ bias,
                                 const float* __restrict__ data,
                                 float* __restrict__ out, int n_nodes) {
  int n = blockIdx.x * blockDim.x + threadIdx.x;
  if (n >= n_nodes) return;
  int e0 = indptr[n], e1 = indptr[n + 1];
  float b00 = 0.f, b01 = 0.f, b10 = 0.f, b11 = 0.f;
  int p = e0;
  for (; p + 2 <= e1; p += 2) {
    int s0 = csr_src[p], s1 = csr_src[p + 1];
    const float* x0 = xpc + (size_t)s0 * 12;
    const float* x1 = xpc + (size_t)s1 * 12;
#pragma unroll
    for (int h = 0; h < HEADS; ++h) {
      float c0 = coef[(size_t)p * HEADS + h];
      float c1 = coef[(size_t)(p + 1) * HEADS + h];
      b00 += c0 * x0[2 * h]; b01 += c0 * x0[2 * h + 1];
      b10 += c1 * x1[2 * h]; b11 += c1 * x1[2 * h + 1];
    }
  }
  if (p < e1) {
    int s0 = csr_src[p];
    const float* x0 = xpc + (size_t)s0 * 12;
#pragma unroll
    for (int h = 0; h < HEADS; ++h) {
      float c0 = coef[(size_t)p * HEADS + h];
      b00 += c0 * x0[2 * h]; b01 += c0 * x0[2 * h + 1];
    }
  }
  float c0 = (b00 + b10) * (1.f / HEADS) + bias[0];
  float c1 = (b01 + b11) * (1.f / HEADS) + bias[1];
  float d0 = data[(size_t)n * NF_IN + 0];
  float d1 = data[(size_t)n * NF_IN + 1];
  if (d0 == 1.f) c0 = 1.f;
  if (d0 == 0.f) c0 = 0.f;
  if (d1 == 0.f) c1 = 0.f;
  if (d1 == 1.f) c1 = 1.f;
  out[(size_t)n * 2 + 0] = c0;
  out[(size_t)n * 2 + 1] = c1;
}

extern "C" void kernel_launch(void* const* d_in, const int* in_sizes, int n_in,
                              void* d_out, int out_size, void* d_ws, size_t ws_size,
                              hipStream_t stream) {
  const float* data = (const float*)d_in[0];
  const int* ei = (const int*)d_in[1];
  const float* W_coord = (const float*)d_in[2];
  const float* att_src_coord = (const float*)d_in[3];
  const float* att_dst_coord = (const float*)d_in[4];
  const float* b_coord = (const float*)d_in[5];
  const float* W_feat = (const float*)d_in[6];
  const float* att_src_feat = (const float*)d_in[7];
  const float* att_dst_feat = (const float*)d_in[8];
  const float* b_feat = (const float*)d_in[9];
  float* out = (float*)d_out;

  const int n = in_sizes[0] / NF_IN;   // 20000
  const int E = in_sizes[1] / 2;       // 160000
  const int Et = E + n;
  const int Mpad = ((n + GBM - 1) / GBM) * GBM;  // 20096

  char* ws = (char*)d_ws;
  size_t o = 0;
  unsigned short* xp_feat = (unsigned short*)(ws + o); o += (size_t)n * NCOLS * 2;
  unsigned short* data_bf = (unsigned short*)(ws + o); o += (size_t)Mpad * NF_IN * 2;
  unsigned short* wt_bf = (unsigned short*)(ws + o); o += (size_t)NCOLS * NF_IN * 2;
  float* xp_coord = (float*)(ws + o); o += (size_t)n * 12 * 4;
  float* asc = (float*)(ws + o); o += (size_t)n * HEADS * 4;
  float* adc = (float*)(ws + o); o += (size_t)n * HEADS * 4;
  // contiguous zero region: asf, adf, counts, fill  (n*14 words)
  float* asf = (float*)(ws + o); o += (size_t)n * HEADS * 4;
  float* adf = (float*)(ws + o); o += (size_t)n * HEADS * 4;
  int* counts = (int*)(ws + o); o += (size_t)n * 4;
  int* fill = (int*)(ws + o); o += (size_t)n * 4;
  int* indptr = (int*)(ws + o); o += ((size_t)n + 32) * 4;
  int* csr_src = (int*)(ws + o); o += (size_t)Et * 4;
  float* coef_f = (float*)(ws + o); o += (size_t)Et * HEADS * 4;
  float* coef_c = (float*)(ws + o); o += (size_t)Et * HEADS * 4;
  if (o > ws_size) return;  // workspace insufficient — fail loudly

  // 1. zero asf/adf/counts/fill (contiguous, n*14 words)
  zero_kernel<<<(14 * n + 255) / 256, 256, 0, stream>>>((int*)asf, 14 * n);
  // 2. fused convert + coord rows
  prep_data_kernel<<<(Mpad + 3) / 4, 256, 0, stream>>>(data, W_coord, att_src_coord,
                                                       att_dst_coord, data_bf, xp_coord,
                                                       asc, adc, n, Mpad);
  // 3. transpose W_feat
  {
    dim3 grid(NCOLS / 32, NF_IN / 32);
    transpose_w_kernel<<<grid, 256, 0, stream>>>(W_feat, wt_bf);
  }
  // 4. feat GEMM (bf16 MFMA) + fused scores
  {
    dim3 grid(NCOLS / GBN, Mpad / GBM);
    gemm_mfma_kernel<<<grid, 256, 0, stream>>>(data_bf, wt_bf, xp_feat,
                                               att_src_feat, att_dst_feat, asf, adf, n);
  }
  // 5. count edges
  count_edges_kernel<<<(Et + 255) / 256, 256, 0, stream>>>(ei, E, Et, counts);
  // 6. scan
  scan_kernel<<<1, 1024, 0, stream>>>(counts, indptr, n);
  // 7. scatter
  scatter_kernel<<<(Et + 255) / 256, 256, 0, stream>>>(ei, E, Et, indptr, fill, csr_src);
  // 8. fused softmax coefs (feat + coord in one walk)
  {
    int nb = (n * HEADS + 255) / 256;
    softmax2_kernel<<<nb, 256, 0, stream>>>(asf, adf, asc, adc, indptr, csr_src,
                                            coef_f, coef_c, n);
  }
  // 9. feat aggregation (persistent grid-stride) -> out[2n ..]
  agg_feat_kernel<<<2048, 256, 0, stream>>>(xp_feat, coef_f, indptr, csr_src,
                                            b_feat, out + (size_t)n * 2, n);
  // 10. coord aggregation + boundary -> out[0 .. 2n)
  agg_coord_kernel<<<(n + 255) / 256, 256, 0, stream>>>(xp_coord, coef_c, indptr, csr_src,
                                                        b_coord, data, out, n);
}

// Round 6
// 274.180 us; speedup vs baseline: 1.0945x; 1.0945x over previous
//
#include <hip/hip_runtime.h>
#include <hip/hip_bf16.h>
#include <math.h>

#define NF_IN 512
#define NF_OUT 256
#define HEADS 6
#define NCOLS (HEADS * NF_OUT)   // 1536
#define SLOPE 0.2f

typedef __attribute__((ext_vector_type(8))) short short8;
typedef __attribute__((ext_vector_type(4))) float f32x4;

__device__ __forceinline__ float bf2f(unsigned short u) {
  unsigned int x = ((unsigned int)u) << 16;
  return __uint_as_float(x);
}
__device__ __forceinline__ unsigned short f2bf(float f) {
  unsigned int x = __float_as_uint(f);
  unsigned int lsb = (x >> 16) & 1u;
  x += 0x7fffu + lsb;
  return (unsigned short)(x >> 16);
}

__device__ __forceinline__ void gload_lds16(const void* g, void* l) {
  __builtin_amdgcn_global_load_lds(
      (const __attribute__((address_space(1))) void*)g,
      (__attribute__((address_space(3))) void*)l, 16, 0, 0);
}

// ---------------- zero init ----------------
__global__ void zero_kernel(int* __restrict__ p, int n) {
  int i = blockIdx.x * blockDim.x + threadIdx.x;
  if (i < n) p[i] = 0;
}

// ---------------- fused: data->bf16 convert + coord matvec + coord scores ----------------
__global__ __launch_bounds__(256) void prep_data_kernel(
    const float* __restrict__ data, const float* __restrict__ W,
    const float* __restrict__ att_src, const float* __restrict__ att_dst,
    unsigned short* __restrict__ data_bf, float* __restrict__ xp,
    float* __restrict__ a_src, float* __restrict__ a_dst, int n_nodes, int m_pad) {
  __shared__ float Ws[NF_IN * 12];
  int t = threadIdx.x;
#pragma unroll
  for (int i = 0; i < 6; ++i)
    *(float4*)(Ws + (i * 256 + t) * 4) = *(const float4*)(W + (i * 256 + t) * 4);
  __syncthreads();
  int warp = t >> 6, lane = t & 63;
  int n = blockIdx.x * 4 + warp;
  if (n >= m_pad) return;
  if (n >= n_nodes) {  // pad rows: zero bf16
    ushort4 z = {0, 0, 0, 0};
    *(ushort4*)(data_bf + (size_t)n * NF_IN + lane * 4) = z;
    *(ushort4*)(data_bf + (size_t)n * NF_IN + 256 + lane * 4) = z;
    return;
  }
  const float* row = data + (size_t)n * NF_IN;
  float x[8];
  *(float4*)(x) = *(const float4*)(row + lane * 4);
  *(float4*)(x + 4) = *(const float4*)(row + 256 + lane * 4);
  ushort4 u0, u1;
  u0.x = f2bf(x[0]); u0.y = f2bf(x[1]); u0.z = f2bf(x[2]); u0.w = f2bf(x[3]);
  u1.x = f2bf(x[4]); u1.y = f2bf(x[5]); u1.z = f2bf(x[6]); u1.w = f2bf(x[7]);
  *(ushort4*)(data_bf + (size_t)n * NF_IN + lane * 4) = u0;
  *(ushort4*)(data_bf + (size_t)n * NF_IN + 256 + lane * 4) = u1;
  float acc[12];
#pragma unroll
  for (int o = 0; o < 12; ++o) acc[o] = 0.f;
#pragma unroll
  for (int j = 0; j < 8; ++j) {
    int c = (j < 4) ? (lane * 4 + j) : (256 + lane * 4 + (j - 4));
    const float* wr = Ws + c * 12;
#pragma unroll
    for (int o = 0; o < 12; ++o) acc[o] += x[j] * wr[o];
  }
#pragma unroll
  for (int o = 0; o < 12; ++o) {
#pragma unroll
    for (int off = 32; off; off >>= 1) acc[o] += __shfl_xor(acc[o], off, 64);
  }
  if (lane == 0) {
    float* xr = xp + (size_t)n * 12;
#pragma unroll
    for (int o = 0; o < 12; ++o) xr[o] = acc[o];
#pragma unroll
    for (int h = 0; h < HEADS; ++h) {
      a_src[n * HEADS + h] = acc[2 * h] * att_src[2 * h] + acc[2 * h + 1] * att_src[2 * h + 1];
      a_dst[n * HEADS + h] = acc[2 * h] * att_dst[2 * h] + acc[2 * h + 1] * att_dst[2 * h + 1];
    }
  }
}

// ---------------- W_feat [512][1536] fp32 -> Wt [1536][512] bf16 ----------------
__global__ __launch_bounds__(256) void transpose_w_kernel(
    const float* __restrict__ W, unsigned short* __restrict__ Wt) {
  __shared__ float tileS[32][33];
  int c0 = blockIdx.x * 32;
  int k0 = blockIdx.y * 32;
  int t = threadIdx.x;
  int tr = t >> 5;
  int tc = t & 31;
#pragma unroll
  for (int j = 0; j < 4; ++j)
    tileS[tr * 4 + j][tc] = W[(size_t)(k0 + tr * 4 + j) * NCOLS + c0 + tc];
  __syncthreads();
#pragma unroll
  for (int j = 0; j < 4; ++j)
    Wt[(size_t)(c0 + tr * 4 + j) * NF_IN + k0 + tc] = f2bf(tileS[tc][tr * 4 + j]);
}

// ---------------- bf16 MFMA GEMM, XOR-swizzled LDS ----------------
// Logical LDS tile [128][32] elems; phys col = col ^ (((row>>1)&3)<<3).
// Staging keeps LDS linear (global_load_lds) and pre-swizzles the GLOBAL
// source column; reads apply the same XOR -> b128 reads hit all 8 granules
// (2-way only, free).
#define GBM 128
#define GBN 128
#define GBK 32
__global__ __launch_bounds__(256) void gemm_mfma_kernel(
    const unsigned short* __restrict__ A, const unsigned short* __restrict__ Bt,
    unsigned short* __restrict__ C, int M) {
  __shared__ __align__(16) unsigned short sA[GBM * GBK];
  __shared__ __align__(16) unsigned short sB[GBN * GBK];
  const int tid = threadIdx.x;
  const int wid = tid >> 6;
  const int lane = tid & 63;
  const int row0 = blockIdx.y * GBM;
  const int col0 = blockIdx.x * GBN;
  const int wr = (wid >> 1) * 64;
  const int wc = (wid & 1) * 64;

  f32x4 acc[4][4] = {};

  const int arow = tid >> 2;        // dest row (phys) for this thread's 8-elem chunk
  const int kseg = tid & 3;
  const int sst = ((arow >> 1) & 3) << 3;     // elem swizzle, same for row and row+64
  const unsigned short* gA = A + (size_t)(row0 + arow) * NF_IN + ((kseg * 8) ^ sst);
  const unsigned short* gB = Bt + (size_t)(col0 + arow) * NF_IN + ((kseg * 8) ^ sst);
  unsigned short* lA = sA + wid * 512;
  unsigned short* lB = sB + wid * 512;

  const int fr = lane & 15;
  const int fk = (lane >> 4) * 8;
  const int fks = fk ^ (((fr >> 1) & 3) << 3);  // swizzled read col

  for (int k0 = 0; k0 < NF_IN; k0 += GBK) {
    gload_lds16(gA + k0, lA);
    gload_lds16(gA + 64 * NF_IN + k0, lA + 2048);
    gload_lds16(gB + k0, lB);
    gload_lds16(gB + 64 * NF_IN + k0, lB + 2048);
    __syncthreads();
    short8 af[4], bfr[4];
#pragma unroll
    for (int m = 0; m < 4; ++m)
      af[m] = *(const short8*)(sA + (wr + m * 16 + fr) * GBK + fks);
#pragma unroll
    for (int nn = 0; nn < 4; ++nn)
      bfr[nn] = *(const short8*)(sB + (wc + nn * 16 + fr) * GBK + fks);
#pragma unroll
    for (int m = 0; m < 4; ++m)
#pragma unroll
      for (int nn = 0; nn < 4; ++nn)
        acc[m][nn] = __builtin_amdgcn_mfma_f32_16x16x32_bf16(af[m], bfr[nn],
                                                             acc[m][nn], 0, 0, 0);
    __syncthreads();
  }

  const int dcol = lane & 15;
  const int g4 = (lane >> 4) * 4;
#pragma unroll
  for (int m = 0; m < 4; ++m) {
#pragma unroll
    for (int i = 0; i < 4; ++i) {
      int r = row0 + wr + m * 16 + g4 + i;
      if (r < M) {
#pragma unroll
        for (int nn = 0; nn < 4; ++nn)
          C[(size_t)r * NCOLS + col0 + wc + nn * 16 + dcol] = f2bf(acc[m][nn][i]);
      }
    }
  }
}

// ---------------- feat attention scores ----------------
__global__ __launch_bounds__(384) void feat_scores_kernel(
    const unsigned short* __restrict__ xp, const float* __restrict__ att_src,
    const float* __restrict__ att_dst, float* __restrict__ a_src,
    float* __restrict__ a_dst) {
  int n = blockIdx.x;
  int h = threadIdx.x >> 6;
  int lane = threadIdx.x & 63;
  ushort4 u = *(const ushort4*)(xp + (size_t)n * NCOLS + h * NF_OUT + lane * 4);
  float4 ws = *(const float4*)(att_src + h * NF_OUT + lane * 4);
  float4 wd = *(const float4*)(att_dst + h * NF_OUT + lane * 4);
  float x0 = bf2f(u.x), x1 = bf2f(u.y), x2 = bf2f(u.z), x3 = bf2f(u.w);
  float ss = x0 * ws.x + x1 * ws.y + x2 * ws.z + x3 * ws.w;
  float sd = x0 * wd.x + x1 * wd.y + x2 * wd.z + x3 * wd.w;
#pragma unroll
  for (int off = 32; off; off >>= 1) {
    ss += __shfl_xor(ss, off, 64);
    sd += __shfl_xor(sd, off, 64);
  }
  if (lane == 0) {
    a_src[n * HEADS + h] = ss;
    a_dst[n * HEADS + h] = sd;
  }
}

// ---------------- edge counting ----------------
__global__ void count_edges_kernel(const int* __restrict__ ei, int E, int Et,
                                   int* __restrict__ counts) {
  int e = blockIdx.x * blockDim.x + threadIdx.x;
  if (e >= Et) return;
  int d = (e < E) ? ei[E + e] : (e - E);
  atomicAdd(&counts[d], 1);
}

// ---------------- fast single-block exclusive scan -> indptr ----------------
__global__ __launch_bounds__(1024) void scan_kernel(const int* __restrict__ counts,
                                                    int* __restrict__ indptr, int n) {
  __shared__ int wsum[16];
  const int CH = (n + 1023) >> 10;
  int t = threadIdx.x, lane = t & 63, w = t >> 6;
  int base = t * CH;
  int run = 0;
  for (int i = 0; i < CH; ++i) {
    int idx = base + i;
    run += (idx < n) ? counts[idx] : 0;
  }
  int tot = run;
#pragma unroll
  for (int off = 1; off < 64; off <<= 1) {
    int x = __shfl_up(tot, off, 64);
    if (lane >= off) tot += x;
  }
  if (lane == 63) wsum[w] = tot;
  __syncthreads();
  if (t == 0) {
    int s = 0;
#pragma unroll
    for (int i = 0; i < 16; ++i) { int x = wsum[i]; wsum[i] = s; s += x; }
  }
  __syncthreads();
  int run2 = wsum[w] + (tot - run);
  if (t == 0) indptr[0] = 0;
  for (int i = 0; i < CH; ++i) {
    int idx = base + i;
    if (idx < n) {
      run2 += counts[idx];
      indptr[idx + 1] = run2;
    }
  }
}

// ---------------- scatter to CSR ----------------
__global__ void scatter_kernel(const int* __restrict__ ei, int E, int Et,
                               const int* __restrict__ indptr, int* __restrict__ fill,
                               int* __restrict__ csr_src) {
  int e = blockIdx.x * blockDim.x + threadIdx.x;
  if (e >= Et) return;
  int s, d;
  if (e < E) { s = ei[e]; d = ei[E + e]; } else { s = d = e - E; }
  int pos = indptr[d] + atomicAdd(&fill[d], 1);
  csr_src[pos] = s;
}

// ---------------- fused per (node, head) edge softmax: feat + coord in one walk ----------------
__global__ void softmax2_kernel(const float* __restrict__ asf, const float* __restrict__ adf,
                                const float* __restrict__ asc, const float* __restrict__ adc,
                                const int* __restrict__ indptr,
                                const int* __restrict__ csr_src,
                                float* __restrict__ coef_f, float* __restrict__ coef_c,
                                int n_nodes) {
  int gid = blockIdx.x * blockDim.x + threadIdx.x;
  if (gid >= n_nodes * HEADS) return;
  int n = gid / HEADS, h = gid - n * HEADS;
  int e0 = indptr[n], e1 = indptr[n + 1];
  float adF = adf[n * HEADS + h];
  float adC = adc[n * HEADS + h];
  float mxF = -1e30f, mxC = -1e30f;
  for (int p = e0; p < e1; ++p) {
    int s = csr_src[p];
    float vF = asf[s * HEADS + h] + adF;
    float vC = asc[s * HEADS + h] + adC;
    vF = (vF >= 0.f) ? vF : SLOPE * vF;
    vC = (vC >= 0.f) ? vC : SLOPE * vC;
    coef_f[(size_t)p * HEADS + h] = vF;
    coef_c[(size_t)p * HEADS + h] = vC;
    mxF = fmaxf(mxF, vF);
    mxC = fmaxf(mxC, vC);
  }
  float sF = 0.f, sC = 0.f;
  for (int p = e0; p < e1; ++p) {
    float eF = __expf(coef_f[(size_t)p * HEADS + h] - mxF);
    float eC = __expf(coef_c[(size_t)p * HEADS + h] - mxC);
    coef_f[(size_t)p * HEADS + h] = eF;
    coef_c[(size_t)p * HEADS + h] = eC;
    sF += eF;
    sC += eC;
  }
  float iF = 1.f / (sF + 1e-16f);
  float iC = 1.f / (sC + 1e-16f);
  for (int p = e0; p < e1; ++p) {
    coef_f[(size_t)p * HEADS + h] *= iF;
    coef_c[(size_t)p * HEADS + h] *= iC;
  }
}

// ---------------- feat aggregation: persistent wave-per-node, grid-stride ----------------
__global__ __launch_bounds__(256) void agg_feat_kernel(
    const unsigned short* __restrict__ xp, const float* __restrict__ coef,
    const int* __restrict__ indptr, const int* __restrict__ csr_src,
    const float* __restrict__ bias, float* __restrict__ out, int n_nodes) {
  int lane = threadIdx.x & 63;
  int gw = blockIdx.x * 4 + (threadIdx.x >> 6);
  int nw = gridDim.x * 4;
  int hhalf = lane >> 5;
  const unsigned short* xpl = xp + lane * 8;

  for (int n = gw; n < n_nodes; n += nw) {
    int e0 = indptr[n], e1 = indptr[n + 1];
    float acc[3][8];
#pragma unroll
    for (int j = 0; j < 3; ++j)
#pragma unroll
      for (int i = 0; i < 8; ++i) acc[j][i] = 0.f;

    int p = e0;
    for (; p + 4 <= e1; p += 4) {
      int s0 = csr_src[p], s1 = csr_src[p + 1], s2 = csr_src[p + 2], s3 = csr_src[p + 3];
      const unsigned short* r0 = xpl + (size_t)s0 * NCOLS;
      const unsigned short* r1 = xpl + (size_t)s1 * NCOLS;
      const unsigned short* r2 = xpl + (size_t)s2 * NCOLS;
      const unsigned short* r3 = xpl + (size_t)s3 * NCOLS;
      ushort4 u[4][3], v[4][3];
#pragma unroll
      for (int j = 0; j < 3; ++j) {
        u[0][j] = *(const ushort4*)(r0 + j * 512);
        u[1][j] = *(const ushort4*)(r1 + j * 512);
        u[2][j] = *(const ushort4*)(r2 + j * 512);
        u[3][j] = *(const ushort4*)(r3 + j * 512);
        v[0][j] = *(const ushort4*)(r0 + j * 512 + 4);
        v[1][j] = *(const ushort4*)(r1 + j * 512 + 4);
        v[2][j] = *(const ushort4*)(r2 + j * 512 + 4);
        v[3][j] = *(const ushort4*)(r3 + j * 512 + 4);
      }
      float cf[4][3];
#pragma unroll
      for (int e = 0; e < 4; ++e)
#pragma unroll
        for (int j = 0; j < 3; ++j)
          cf[e][j] = coef[(size_t)(p + e) * HEADS + 2 * j + hhalf];
#pragma unroll
      for (int e = 0; e < 4; ++e)
#pragma unroll
        for (int j = 0; j < 3; ++j) {
          float c = cf[e][j];
          acc[j][0] += c * bf2f(u[e][j].x);
          acc[j][1] += c * bf2f(u[e][j].y);
          acc[j][2] += c * bf2f(u[e][j].z);
          acc[j][3] += c * bf2f(u[e][j].w);
          acc[j][4] += c * bf2f(v[e][j].x);
          acc[j][5] += c * bf2f(v[e][j].y);
          acc[j][6] += c * bf2f(v[e][j].z);
          acc[j][7] += c * bf2f(v[e][j].w);
        }
    }
    for (; p < e1; ++p) {
      int s0 = csr_src[p];
      const unsigned short* r0 = xpl + (size_t)s0 * NCOLS;
#pragma unroll
      for (int j = 0; j < 3; ++j) {
        float c = coef[(size_t)p * HEADS + 2 * j + hhalf];
        ushort4 a = *(const ushort4*)(r0 + j * 512);
        ushort4 b = *(const ushort4*)(r0 + j * 512 + 4);
        acc[j][0] += c * bf2f(a.x); acc[j][1] += c * bf2f(a.y);
        acc[j][2] += c * bf2f(a.z); acc[j][3] += c * bf2f(a.w);
        acc[j][4] += c * bf2f(b.x); acc[j][5] += c * bf2f(b.y);
        acc[j][6] += c * bf2f(b.z); acc[j][7] += c * bf2f(b.w);
      }
    }
    float r[8];
#pragma unroll
    for (int i = 0; i < 8; ++i) {
      r[i] = acc[0][i] + acc[1][i] + acc[2][i];
      r[i] += __shfl_xor(r[i], 32, 64);
    }
    if (lane < 32) {
      const float selu_scale = 1.0507009873554805f;
      const float selu_alpha = 1.6732632423543772f;
      int c0 = lane * 8;
#pragma unroll
      for (int i = 0; i < 8; ++i) {
        float v = r[i] * (1.f / HEADS) + bias[c0 + i];
        r[i] = (v > 0.f) ? selu_scale * v : selu_scale * selu_alpha * expm1f(v);
      }
      float4 o0, o1;
      o0.x = r[0]; o0.y = r[1]; o0.z = r[2]; o0.w = r[3];
      o1.x = r[4]; o1.y = r[5]; o1.z = r[6]; o1.w = r[7];
      *(float4*)(out + (size_t)n * NF_OUT + c0) = o0;
      *(float4*)(out + (size_t)n * NF_OUT + c0 + 4) = o1;
    }
  }
}

// ---------------- coord aggregation + boundary fix (2-edge ILP) ----------------
__global__ void agg_coord_kernel(const float* __restrict__ xpc,
                                 const float* __restrict__ coef,
                                 const int* __restrict__ indptr,
                                 const int* __restrict__ csr_src,
                                 const float* __restrict__ bias,
                                 const float* __restrict__ data,
                                 float* __restrict__ out, int n_nodes) {
  int n = blockIdx.x * blockDim.x + threadIdx.x;
  if (n >= n_nodes) return;
  int e0 = indptr[n], e1 = indptr[n + 1];
  float b00 = 0.f, b01 = 0.f, b10 = 0.f, b11 = 0.f;
  int p = e0;
  for (; p + 2 <= e1; p += 2) {
    int s0 = csr_src[p], s1 = csr_src[p + 1];
    const float* x0 = xpc + (size_t)s0 * 12;
    const float* x1 = xpc + (size_t)s1 * 12;
#pragma unroll
    for (int h = 0; h < HEADS; ++h) {
      float c0 = coef[(size_t)p * HEADS + h];
      float c1 = coef[(size_t)(p + 1) * HEADS + h];
      b00 += c0 * x0[2 * h]; b01 += c0 * x0[2 * h + 1];
      b10 += c1 * x1[2 * h]; b11 += c1 * x1[2 * h + 1];
    }
  }
  if (p < e1) {
    int s0 = csr_src[p];
    const float* x0 = xpc + (size_t)s0 * 12;
#pragma unroll
    for (int h = 0; h < HEADS; ++h) {
      float c0 = coef[(size_t)p * HEADS + h];
      b00 += c0 * x0[2 * h]; b01 += c0 * x0[2 * h + 1];
    }
  }
  float c0 = (b00 + b10) * (1.f / HEADS) + bias[0];
  float c1 = (b01 + b11) * (1.f / HEADS) + bias[1];
  float d0 = data[(size_t)n * NF_IN + 0];
  float d1 = data[(size_t)n * NF_IN + 1];
  if (d0 == 1.f) c0 = 1.f;
  if (d0 == 0.f) c0 = 0.f;
  if (d1 == 0.f) c1 = 0.f;
  if (d1 == 1.f) c1 = 1.f;
  out[(size_t)n * 2 + 0] = c0;
  out[(size_t)n * 2 + 1] = c1;
}

extern "C" void kernel_launch(void* const* d_in, const int* in_sizes, int n_in,
                              void* d_out, int out_size, void* d_ws, size_t ws_size,
                              hipStream_t stream) {
  const float* data = (const float*)d_in[0];
  const int* ei = (const int*)d_in[1];
  const float* W_coord = (const float*)d_in[2];
  const float* att_src_coord = (const float*)d_in[3];
  const float* att_dst_coord = (const float*)d_in[4];
  const float* b_coord = (const float*)d_in[5];
  const float* W_feat = (const float*)d_in[6];
  const float* att_src_feat = (const float*)d_in[7];
  const float* att_dst_feat = (const float*)d_in[8];
  const float* b_feat = (const float*)d_in[9];
  float* out = (float*)d_out;

  const int n = in_sizes[0] / NF_IN;   // 20000
  const int E = in_sizes[1] / 2;       // 160000
  const int Et = E + n;
  const int Mpad = ((n + GBM - 1) / GBM) * GBM;  // 20096

  char* ws = (char*)d_ws;
  size_t o = 0;
  unsigned short* xp_feat = (unsigned short*)(ws + o); o += (size_t)n * NCOLS * 2;
  unsigned short* data_bf = (unsigned short*)(ws + o); o += (size_t)Mpad * NF_IN * 2;
  unsigned short* wt_bf = (unsigned short*)(ws + o); o += (size_t)NCOLS * NF_IN * 2;
  float* xp_coord = (float*)(ws + o); o += (size_t)n * 12 * 4;
  float* asf = (float*)(ws + o); o += (size_t)n * HEADS * 4;
  float* adf = (float*)(ws + o); o += (size_t)n * HEADS * 4;
  float* asc = (float*)(ws + o); o += (size_t)n * HEADS * 4;
  float* adc = (float*)(ws + o); o += (size_t)n * HEADS * 4;
  int* counts = (int*)(ws + o); o += (size_t)n * 4;
  int* fill = (int*)(ws + o); o += (size_t)n * 4;
  int* indptr = (int*)(ws + o); o += ((size_t)n + 32) * 4;
  int* csr_src = (int*)(ws + o); o += (size_t)Et * 4;
  float* coef_f = (float*)(ws + o); o += (size_t)Et * HEADS * 4;
  float* coef_c = (float*)(ws + o); o += (size_t)Et * HEADS * 4;
  if (o > ws_size) return;  // workspace insufficient — fail loudly

  // 1. zero counts+fill (contiguous)
  zero_kernel<<<(2 * n + 255) / 256, 256, 0, stream>>>(counts, 2 * n);
  // 2. fused convert + coord rows
  prep_data_kernel<<<(Mpad + 3) / 4, 256, 0, stream>>>(data, W_coord, att_src_coord,
                                                       att_dst_coord, data_bf, xp_coord,
                                                       asc, adc, n, Mpad);
  // 3. transpose W_feat
  {
    dim3 grid(NCOLS / 32, NF_IN / 32);
    transpose_w_kernel<<<grid, 256, 0, stream>>>(W_feat, wt_bf);
  }
  // 4. feat GEMM (bf16 MFMA, swizzled LDS)
  {
    dim3 grid(NCOLS / GBN, Mpad / GBM);
    gemm_mfma_kernel<<<grid, 256, 0, stream>>>(data_bf, wt_bf, xp_feat, n);
  }
  // 5. feat scores
  feat_scores_kernel<<<n, 384, 0, stream>>>(xp_feat, att_src_feat, att_dst_feat, asf, adf);
  // 6. count edges
  count_edges_kernel<<<(Et + 255) / 256, 256, 0, stream>>>(ei, E, Et, counts);
  // 7. scan
  scan_kernel<<<1, 1024, 0, stream>>>(counts, indptr, n);
  // 8. scatter
  scatter_kernel<<<(Et + 255) / 256, 256, 0, stream>>>(ei, E, Et, indptr, fill, csr_src);
  // 9. fused softmax coefs (feat + coord in one walk)
  {
    int nb = (n * HEADS + 255) / 256;
    softmax2_kernel<<<nb, 256, 0, stream>>>(asf, adf, asc, adc, indptr, csr_src,
                                            coef_f, coef_c, n);
  }
  // 10. feat aggregation (persistent grid-stride) -> out[2n ..]
  agg_feat_kernel<<<2048, 256, 0, stream>>>(xp_feat, coef_f, indptr, csr_src,
                                            b_feat, out + (size_t)n * 2, n);
  // 11. coord aggregation + boundary -> out[0 .. 2n)
  agg_coord_kernel<<<(n + 255) / 256, 256, 0, stream>>>(xp_coord, coef_c, indptr, csr_src,
                                                        b_coord, data, out, n);
}

// Round 7
// 266.306 us; speedup vs baseline: 1.1268x; 1.0296x over previous
//
#include <hip/hip_runtime.h>
#include <hip/hip_bf16.h>
#include <math.h>

#define NF_IN 512
#define NF_OUT 256
#define HEADS 6
#define NCOLS (HEADS * NF_OUT)   // 1536
#define SLOPE 0.2f

typedef __attribute__((ext_vector_type(8))) short short8;
typedef __attribute__((ext_vector_type(4))) float f32x4;

__device__ __forceinline__ float bf2f(unsigned short u) {
  unsigned int x = ((unsigned int)u) << 16;
  return __uint_as_float(x);
}
__device__ __forceinline__ unsigned short f2bf(float f) {
  unsigned int x = __float_as_uint(f);
  unsigned int lsb = (x >> 16) & 1u;
  x += 0x7fffu + lsb;
  return (unsigned short)(x >> 16);
}

__device__ __forceinline__ void gload_lds16(const void* g, void* l) {
  __builtin_amdgcn_global_load_lds(
      (const __attribute__((address_space(1))) void*)g,
      (__attribute__((address_space(3))) void*)l, 16, 0, 0);
}

// ---------------- zero init ----------------
__global__ void zero_kernel(int* __restrict__ p, int n) {
  int i = blockIdx.x * blockDim.x + threadIdx.x;
  if (i < n) p[i] = 0;
}

// ---------------- fused: data->bf16 convert + coord matvec + coord scores ----------------
__global__ __launch_bounds__(256) void prep_data_kernel(
    const float* __restrict__ data, const float* __restrict__ W,
    const float* __restrict__ att_src, const float* __restrict__ att_dst,
    unsigned short* __restrict__ data_bf, float* __restrict__ xp,
    float* __restrict__ a_src, float* __restrict__ a_dst, int n_nodes, int m_pad) {
  __shared__ float Ws[NF_IN * 12];
  int t = threadIdx.x;
#pragma unroll
  for (int i = 0; i < 6; ++i)
    *(float4*)(Ws + (i * 256 + t) * 4) = *(const float4*)(W + (i * 256 + t) * 4);
  __syncthreads();
  int warp = t >> 6, lane = t & 63;
  int n = blockIdx.x * 4 + warp;
  if (n >= m_pad) return;
  if (n >= n_nodes) {  // pad rows: zero bf16
    ushort4 z = {0, 0, 0, 0};
    *(ushort4*)(data_bf + (size_t)n * NF_IN + lane * 4) = z;
    *(ushort4*)(data_bf + (size_t)n * NF_IN + 256 + lane * 4) = z;
    return;
  }
  const float* row = data + (size_t)n * NF_IN;
  float x[8];
  *(float4*)(x) = *(const float4*)(row + lane * 4);
  *(float4*)(x + 4) = *(const float4*)(row + 256 + lane * 4);
  ushort4 u0, u1;
  u0.x = f2bf(x[0]); u0.y = f2bf(x[1]); u0.z = f2bf(x[2]); u0.w = f2bf(x[3]);
  u1.x = f2bf(x[4]); u1.y = f2bf(x[5]); u1.z = f2bf(x[6]); u1.w = f2bf(x[7]);
  *(ushort4*)(data_bf + (size_t)n * NF_IN + lane * 4) = u0;
  *(ushort4*)(data_bf + (size_t)n * NF_IN + 256 + lane * 4) = u1;
  float acc[12];
#pragma unroll
  for (int o = 0; o < 12; ++o) acc[o] = 0.f;
#pragma unroll
  for (int j = 0; j < 8; ++j) {
    int c = (j < 4) ? (lane * 4 + j) : (256 + lane * 4 + (j - 4));
    const float* wr = Ws + c * 12;
#pragma unroll
    for (int o = 0; o < 12; ++o) acc[o] += x[j] * wr[o];
  }
#pragma unroll
  for (int o = 0; o < 12; ++o) {
#pragma unroll
    for (int off = 32; off; off >>= 1) acc[o] += __shfl_xor(acc[o], off, 64);
  }
  if (lane == 0) {
    float* xr = xp + (size_t)n * 12;
#pragma unroll
    for (int o = 0; o < 12; ++o) xr[o] = acc[o];
#pragma unroll
    for (int h = 0; h < HEADS; ++h) {
      a_src[n * HEADS + h] = acc[2 * h] * att_src[2 * h] + acc[2 * h + 1] * att_src[2 * h + 1];
      a_dst[n * HEADS + h] = acc[2 * h] * att_dst[2 * h] + acc[2 * h + 1] * att_dst[2 * h + 1];
    }
  }
}

// ---------------- W_feat [512][1536] fp32 -> Wt [1536][512] bf16 ----------------
__global__ __launch_bounds__(256) void transpose_w_kernel(
    const float* __restrict__ W, unsigned short* __restrict__ Wt) {
  __shared__ float tileS[32][33];
  int c0 = blockIdx.x * 32;
  int k0 = blockIdx.y * 32;
  int t = threadIdx.x;
  int tr = t >> 5;
  int tc = t & 31;
#pragma unroll
  for (int j = 0; j < 4; ++j)
    tileS[tr * 4 + j][tc] = W[(size_t)(k0 + tr * 4 + j) * NCOLS + c0 + tc];
  __syncthreads();
#pragma unroll
  for (int j = 0; j < 4; ++j)
    Wt[(size_t)(c0 + tr * 4 + j) * NF_IN + k0 + tc] = f2bf(tileS[tc][tr * 4 + j]);
}

// ---------------- bf16 MFMA GEMM, XOR-swizzled LDS ----------------
#define GBM 128
#define GBN 128
#define GBK 32
__global__ __launch_bounds__(256) void gemm_mfma_kernel(
    const unsigned short* __restrict__ A, const unsigned short* __restrict__ Bt,
    unsigned short* __restrict__ C, int M) {
  __shared__ __align__(16) unsigned short sA[GBM * GBK];
  __shared__ __align__(16) unsigned short sB[GBN * GBK];
  const int tid = threadIdx.x;
  const int wid = tid >> 6;
  const int lane = tid & 63;
  const int row0 = blockIdx.y * GBM;
  const int col0 = blockIdx.x * GBN;
  const int wr = (wid >> 1) * 64;
  const int wc = (wid & 1) * 64;

  f32x4 acc[4][4] = {};

  const int arow = tid >> 2;
  const int kseg = tid & 3;
  const int sst = ((arow >> 1) & 3) << 3;
  const unsigned short* gA = A + (size_t)(row0 + arow) * NF_IN + ((kseg * 8) ^ sst);
  const unsigned short* gB = Bt + (size_t)(col0 + arow) * NF_IN + ((kseg * 8) ^ sst);
  unsigned short* lA = sA + wid * 512;
  unsigned short* lB = sB + wid * 512;

  const int fr = lane & 15;
  const int fk = (lane >> 4) * 8;
  const int fks = fk ^ (((fr >> 1) & 3) << 3);

  for (int k0 = 0; k0 < NF_IN; k0 += GBK) {
    gload_lds16(gA + k0, lA);
    gload_lds16(gA + 64 * NF_IN + k0, lA + 2048);
    gload_lds16(gB + k0, lB);
    gload_lds16(gB + 64 * NF_IN + k0, lB + 2048);
    __syncthreads();
    short8 af[4], bfr[4];
#pragma unroll
    for (int m = 0; m < 4; ++m)
      af[m] = *(const short8*)(sA + (wr + m * 16 + fr) * GBK + fks);
#pragma unroll
    for (int nn = 0; nn < 4; ++nn)
      bfr[nn] = *(const short8*)(sB + (wc + nn * 16 + fr) * GBK + fks);
#pragma unroll
    for (int m = 0; m < 4; ++m)
#pragma unroll
      for (int nn = 0; nn < 4; ++nn)
        acc[m][nn] = __builtin_amdgcn_mfma_f32_16x16x32_bf16(af[m], bfr[nn],
                                                             acc[m][nn], 0, 0, 0);
    __syncthreads();
  }

  const int dcol = lane & 15;
  const int g4 = (lane >> 4) * 4;
#pragma unroll
  for (int m = 0; m < 4; ++m) {
#pragma unroll
    for (int i = 0; i < 4; ++i) {
      int r = row0 + wr + m * 16 + g4 + i;
      if (r < M) {
#pragma unroll
        for (int nn = 0; nn < 4; ++nn)
          C[(size_t)r * NCOLS + col0 + wc + nn * 16 + dcol] = f2bf(acc[m][nn][i]);
      }
    }
  }
}

// ---------------- feat attention scores ----------------
__global__ __launch_bounds__(384) void feat_scores_kernel(
    const unsigned short* __restrict__ xp, const float* __restrict__ att_src,
    const float* __restrict__ att_dst, float* __restrict__ a_src,
    float* __restrict__ a_dst) {
  int n = blockIdx.x;
  int h = threadIdx.x >> 6;
  int lane = threadIdx.x & 63;
  ushort4 u = *(const ushort4*)(xp + (size_t)n * NCOLS + h * NF_OUT + lane * 4);
  float4 ws = *(const float4*)(att_src + h * NF_OUT + lane * 4);
  float4 wd = *(const float4*)(att_dst + h * NF_OUT + lane * 4);
  float x0 = bf2f(u.x), x1 = bf2f(u.y), x2 = bf2f(u.z), x3 = bf2f(u.w);
  float ss = x0 * ws.x + x1 * ws.y + x2 * ws.z + x3 * ws.w;
  float sd = x0 * wd.x + x1 * wd.y + x2 * wd.z + x3 * wd.w;
#pragma unroll
  for (int off = 32; off; off >>= 1) {
    ss += __shfl_xor(ss, off, 64);
    sd += __shfl_xor(sd, off, 64);
  }
  if (lane == 0) {
    a_src[n * HEADS + h] = ss;
    a_dst[n * HEADS + h] = sd;
  }
}

// ---------------- edge counting ----------------
__global__ void count_edges_kernel(const int* __restrict__ ei, int E, int Et,
                                   int* __restrict__ counts) {
  int e = blockIdx.x * blockDim.x + threadIdx.x;
  if (e >= Et) return;
  int d = (e < E) ? ei[E + e] : (e - E);
  atomicAdd(&counts[d], 1);
}

// ---------------- fast single-block exclusive scan -> indptr ----------------
__global__ __launch_bounds__(1024) void scan_kernel(const int* __restrict__ counts,
                                                    int* __restrict__ indptr, int n) {
  __shared__ int wsum[16];
  const int CH = (n + 1023) >> 10;
  int t = threadIdx.x, lane = t & 63, w = t >> 6;
  int base = t * CH;
  int run = 0;
  for (int i = 0; i < CH; ++i) {
    int idx = base + i;
    run += (idx < n) ? counts[idx] : 0;
  }
  int tot = run;
#pragma unroll
  for (int off = 1; off < 64; off <<= 1) {
    int x = __shfl_up(tot, off, 64);
    if (lane >= off) tot += x;
  }
  if (lane == 63) wsum[w] = tot;
  __syncthreads();
  if (t == 0) {
    int s = 0;
#pragma unroll
    for (int i = 0; i < 16; ++i) { int x = wsum[i]; wsum[i] = s; s += x; }
  }
  __syncthreads();
  int run2 = wsum[w] + (tot - run);
  if (t == 0) indptr[0] = 0;
  for (int i = 0; i < CH; ++i) {
    int idx = base + i;
    if (idx < n) {
      run2 += counts[idx];
      indptr[idx + 1] = run2;
    }
  }
}

// ---------------- scatter to CSR ----------------
__global__ void scatter_kernel(const int* __restrict__ ei, int E, int Et,
                               const int* __restrict__ indptr, int* __restrict__ fill,
                               int* __restrict__ csr_src) {
  int e = blockIdx.x * blockDim.x + threadIdx.x;
  if (e >= Et) return;
  int s, d;
  if (e < E) { s = ei[e]; d = ei[E + e]; } else { s = d = e - E; }
  int pos = indptr[d] + atomicAdd(&fill[d], 1);
  csr_src[pos] = s;
}

// ---------------- fused softmax (feat+coord) + coord aggregation + boundary ----------------
// 8 lanes per node; lanes 0-5 = heads, 6-7 idle. Coord output reduced via
// width-8 shfl_xor, written by lane 0. coef_f gets the normalized feat coefs
// for agg_feat; coef_c is pure scratch (normalization folded into pass 3).
__global__ __launch_bounds__(256) void softmax_coord_kernel(
    const float* __restrict__ asf, const float* __restrict__ adf,
    const float* __restrict__ asc, const float* __restrict__ adc,
    const int* __restrict__ indptr, const int* __restrict__ csr_src,
    const float* __restrict__ xpc, const float* __restrict__ b_coord,
    const float* __restrict__ data, float* __restrict__ coef_f,
    float* __restrict__ coef_c, float* __restrict__ out_coord, int n_nodes) {
  int gid = blockIdx.x * blockDim.x + threadIdx.x;
  int n = gid >> 3;
  int h = gid & 7;
  bool act = (n < n_nodes) && (h < HEADS);
  int e0 = 0, e1 = 0;
  float adF = 0.f, adC = 0.f;
  if (act) {
    e0 = indptr[n];
    e1 = indptr[n + 1];
    adF = adf[n * HEADS + h];
    adC = adc[n * HEADS + h];
  }
  float mxF = -1e30f, mxC = -1e30f;
  for (int p = e0; p < e1; ++p) {
    int s = csr_src[p];
    float vF = asf[s * HEADS + h] + adF;
    float vC = asc[s * HEADS + h] + adC;
    vF = (vF >= 0.f) ? vF : SLOPE * vF;
    vC = (vC >= 0.f) ? vC : SLOPE * vC;
    coef_f[(size_t)p * HEADS + h] = vF;
    coef_c[(size_t)p * HEADS + h] = vC;
    mxF = fmaxf(mxF, vF);
    mxC = fmaxf(mxC, vC);
  }
  float sF = 0.f, sC = 0.f;
  for (int p = e0; p < e1; ++p) {
    float eF = __expf(coef_f[(size_t)p * HEADS + h] - mxF);
    float eC = __expf(coef_c[(size_t)p * HEADS + h] - mxC);
    coef_f[(size_t)p * HEADS + h] = eF;
    coef_c[(size_t)p * HEADS + h] = eC;
    sF += eF;
    sC += eC;
  }
  float iF = 1.f / (sF + 1e-16f);
  float iC = (1.f / (sC + 1e-16f)) * (1.f / HEADS);
  float c0 = 0.f, c1 = 0.f;
  for (int p = e0; p < e1; ++p) {
    int s = csr_src[p];
    coef_f[(size_t)p * HEADS + h] *= iF;
    float cc = coef_c[(size_t)p * HEADS + h] * iC;
    c0 += cc * xpc[(size_t)s * 12 + 2 * h];
    c1 += cc * xpc[(size_t)s * 12 + 2 * h + 1];
  }
#pragma unroll
  for (int off = 1; off < 8; off <<= 1) {
    c0 += __shfl_xor(c0, off, 8);
    c1 += __shfl_xor(c1, off, 8);
  }
  if (h == 0 && n < n_nodes) {
    c0 += b_coord[0];
    c1 += b_coord[1];
    float d0 = data[(size_t)n * NF_IN + 0];
    float d1 = data[(size_t)n * NF_IN + 1];
    if (d0 == 1.f) c0 = 1.f;
    if (d0 == 0.f) c0 = 0.f;
    if (d1 == 0.f) c1 = 0.f;
    if (d1 == 1.f) c1 = 1.f;
    out_coord[(size_t)n * 2 + 0] = c0;
    out_coord[(size_t)n * 2 + 1] = c1;
  }
}

// ---------------- feat aggregation: persistent wave-per-node, 16-B gathers ----------------
// Lane l, chunk j covers elems j*512 + l*8 (16 B contiguous per lane):
// head = 2j + (l>>5), col = (l&31)*8. Lane l and l^32 hold complementary head
// triples for the same cols -> one shfl_xor(32); lanes <32 store.
__global__ __launch_bounds__(256) void agg_feat_kernel(
    const unsigned short* __restrict__ xp, const float* __restrict__ coef,
    const int* __restrict__ indptr, const int* __restrict__ csr_src,
    const float* __restrict__ bias, float* __restrict__ out, int n_nodes) {
  int lane = threadIdx.x & 63;
  int gw = blockIdx.x * 4 + (threadIdx.x >> 6);
  int nw = gridDim.x * 4;
  int hhalf = lane >> 5;
  const unsigned short* xpl = xp + lane * 8;

  for (int n = gw; n < n_nodes; n += nw) {
    int e0 = indptr[n], e1 = indptr[n + 1];
    float acc[3][8];
#pragma unroll
    for (int j = 0; j < 3; ++j)
#pragma unroll
      for (int i = 0; i < 8; ++i) acc[j][i] = 0.f;

    int p = e0;
    for (; p + 4 <= e1; p += 4) {
      int s0 = csr_src[p], s1 = csr_src[p + 1], s2 = csr_src[p + 2], s3 = csr_src[p + 3];
      const unsigned short* r0 = xpl + (size_t)s0 * NCOLS;
      const unsigned short* r1 = xpl + (size_t)s1 * NCOLS;
      const unsigned short* r2 = xpl + (size_t)s2 * NCOLS;
      const unsigned short* r3 = xpl + (size_t)s3 * NCOLS;
      short8 w[4][3];
#pragma unroll
      for (int j = 0; j < 3; ++j) {
        w[0][j] = *(const short8*)(r0 + j * 512);
        w[1][j] = *(const short8*)(r1 + j * 512);
        w[2][j] = *(const short8*)(r2 + j * 512);
        w[3][j] = *(const short8*)(r3 + j * 512);
      }
      float cf[4][3];
#pragma unroll
      for (int e = 0; e < 4; ++e)
#pragma unroll
        for (int j = 0; j < 3; ++j)
          cf[e][j] = coef[(size_t)(p + e) * HEADS + 2 * j + hhalf];
#pragma unroll
      for (int e = 0; e < 4; ++e)
#pragma unroll
        for (int j = 0; j < 3; ++j) {
          float c = cf[e][j];
#pragma unroll
          for (int i = 0; i < 8; ++i)
            acc[j][i] += c * bf2f((unsigned short)w[e][j][i]);
        }
    }
    for (; p < e1; ++p) {
      int s0 = csr_src[p];
      const unsigned short* r0 = xpl + (size_t)s0 * NCOLS;
#pragma unroll
      for (int j = 0; j < 3; ++j) {
        float c = coef[(size_t)p * HEADS + 2 * j + hhalf];
        short8 a = *(const short8*)(r0 + j * 512);
#pragma unroll
        for (int i = 0; i < 8; ++i)
          acc[j][i] += c * bf2f((unsigned short)a[i]);
      }
    }
    float r[8];
#pragma unroll
    for (int i = 0; i < 8; ++i) {
      r[i] = acc[0][i] + acc[1][i] + acc[2][i];
      r[i] += __shfl_xor(r[i], 32, 64);
    }
    if (lane < 32) {
      const float selu_scale = 1.0507009873554805f;
      const float selu_alpha = 1.6732632423543772f;
      int c0 = lane * 8;
#pragma unroll
      for (int i = 0; i < 8; ++i) {
        float v = r[i] * (1.f / HEADS) + bias[c0 + i];
        r[i] = (v > 0.f) ? selu_scale * v : selu_scale * selu_alpha * expm1f(v);
      }
      float4 o0, o1;
      o0.x = r[0]; o0.y = r[1]; o0.z = r[2]; o0.w = r[3];
      o1.x = r[4]; o1.y = r[5]; o1.z = r[6]; o1.w = r[7];
      *(float4*)(out + (size_t)n * NF_OUT + c0) = o0;
      *(float4*)(out + (size_t)n * NF_OUT + c0 + 4) = o1;
    }
  }
}

extern "C" void kernel_launch(void* const* d_in, const int* in_sizes, int n_in,
                              void* d_out, int out_size, void* d_ws, size_t ws_size,
                              hipStream_t stream) {
  const float* data = (const float*)d_in[0];
  const int* ei = (const int*)d_in[1];
  const float* W_coord = (const float*)d_in[2];
  const float* att_src_coord = (const float*)d_in[3];
  const float* att_dst_coord = (const float*)d_in[4];
  const float* b_coord = (const float*)d_in[5];
  const float* W_feat = (const float*)d_in[6];
  const float* att_src_feat = (const float*)d_in[7];
  const float* att_dst_feat = (const float*)d_in[8];
  const float* b_feat = (const float*)d_in[9];
  float* out = (float*)d_out;

  const int n = in_sizes[0] / NF_IN;   // 20000
  const int E = in_sizes[1] / 2;       // 160000
  const int Et = E + n;
  const int Mpad = ((n + GBM - 1) / GBM) * GBM;  // 20096

  char* ws = (char*)d_ws;
  size_t o = 0;
  unsigned short* xp_feat = (unsigned short*)(ws + o); o += (size_t)n * NCOLS * 2;
  unsigned short* data_bf = (unsigned short*)(ws + o); o += (size_t)Mpad * NF_IN * 2;
  unsigned short* wt_bf = (unsigned short*)(ws + o); o += (size_t)NCOLS * NF_IN * 2;
  float* xp_coord = (float*)(ws + o); o += (size_t)n * 12 * 4;
  float* asf = (float*)(ws + o); o += (size_t)n * HEADS * 4;
  float* adf = (float*)(ws + o); o += (size_t)n * HEADS * 4;
  float* asc = (float*)(ws + o); o += (size_t)n * HEADS * 4;
  float* adc = (float*)(ws + o); o += (size_t)n * HEADS * 4;
  int* counts = (int*)(ws + o); o += (size_t)n * 4;
  int* fill = (int*)(ws + o); o += (size_t)n * 4;
  int* indptr = (int*)(ws + o); o += ((size_t)n + 32) * 4;
  int* csr_src = (int*)(ws + o); o += (size_t)Et * 4;
  float* coef_f = (float*)(ws + o); o += (size_t)Et * HEADS * 4;
  float* coef_c = (float*)(ws + o); o += (size_t)Et * HEADS * 4;
  if (o > ws_size) return;  // workspace insufficient — fail loudly

  // 1. zero counts+fill (contiguous)
  zero_kernel<<<(2 * n + 255) / 256, 256, 0, stream>>>(counts, 2 * n);
  // 2. fused convert + coord rows
  prep_data_kernel<<<(Mpad + 3) / 4, 256, 0, stream>>>(data, W_coord, att_src_coord,
                                                       att_dst_coord, data_bf, xp_coord,
                                                       asc, adc, n, Mpad);
  // 3. transpose W_feat
  {
    dim3 grid(NCOLS / 32, NF_IN / 32);
    transpose_w_kernel<<<grid, 256, 0, stream>>>(W_feat, wt_bf);
  }
  // 4. feat GEMM (bf16 MFMA, swizzled LDS)
  {
    dim3 grid(NCOLS / GBN, Mpad / GBM);
    gemm_mfma_kernel<<<grid, 256, 0, stream>>>(data_bf, wt_bf, xp_feat, n);
  }
  // 5. feat scores
  feat_scores_kernel<<<n, 384, 0, stream>>>(xp_feat, att_src_feat, att_dst_feat, asf, adf);
  // 6. count edges
  count_edges_kernel<<<(Et + 255) / 256, 256, 0, stream>>>(ei, E, Et, counts);
  // 7. scan
  scan_kernel<<<1, 1024, 0, stream>>>(counts, indptr, n);
  // 8. scatter
  scatter_kernel<<<(Et + 255) / 256, 256, 0, stream>>>(ei, E, Et, indptr, fill, csr_src);
  // 9. fused softmax + coord aggregation + boundary -> out[0 .. 2n)
  {
    int nb = (n * 8 + 255) / 256;
    softmax_coord_kernel<<<nb, 256, 0, stream>>>(asf, adf, asc, adc, indptr, csr_src,
                                                 xp_coord, b_coord, data, coef_f, coef_c,
                                                 out, n);
  }
  // 10. feat aggregation (persistent grid-stride, 16-B gathers) -> out[2n ..]
  agg_feat_kernel<<<2048, 256, 0, stream>>>(xp_feat, coef_f, indptr, csr_src,
                                            b_feat, out + (size_t)n * 2, n);
}